// Round 3
// baseline (679.060 us; speedup 1.0000x reference)
//
#include <hip/hip_runtime.h>
#include <hip/hip_bf16.h>

typedef float f32x4 __attribute__((ext_vector_type(4)));
typedef __bf16 bf16x8 __attribute__((ext_vector_type(8)));
typedef short short8v __attribute__((ext_vector_type(8)));

#define NPTS 131072
#define CDIM 512
#define NCOL 128
#define NSEG 16
#define MB 64
#define BK 32
#define AROW 520            // shorts per A row (512 data + 8 pad) -> 1040 B, 4-bank shift/row
#define BSTR 80             // LDS bytes per B col chunk (64 data + 16 pad)
#define SCLAMP 20.0f

// ---------------- K0: transpose W1 [512][128] f32 -> W1T [128][512] bf16 ----------------
__global__ __launch_bounds__(256)
void k_prep(const float* __restrict__ w1_0, const float* __restrict__ w1_1,
            unsigned short* __restrict__ w1t)
{
    int bid = blockIdx.x;
    int t = bid >> 4, kc = bid & 15;
    const float* src = t ? w1_1 : w1_0;
    __shared__ float lds[32][129];
    int tid = threadIdx.x;
    int kl = tid >> 3, c0 = (tid & 7) * 16;
    const float* p = src + (size_t)(kc * 32 + kl) * 128 + c0;
#pragma unroll
    for (int i = 0; i < 16; i += 4) {
        float4 v = *(const float4*)(p + i);
        lds[kl][c0 + i] = v.x; lds[kl][c0 + i + 1] = v.y;
        lds[kl][c0 + i + 2] = v.z; lds[kl][c0 + i + 3] = v.w;
    }
    __syncthreads();
    int c = tid >> 1, kk0 = (tid & 1) * 16;
    unsigned short buf[16];
#pragma unroll
    for (int i = 0; i < 16; i++) {
        __hip_bfloat16 h = __float2bfloat16(lds[kk0 + i][c]);
        buf[i] = *(unsigned short*)&h;
    }
    unsigned short* dst = w1t + ((size_t)t * 128 + c) * 512 + kc * 32 + kk0;
    *(uint4*)(dst)     = *(uint4*)(buf);
    *(uint4*)(dst + 8) = *(uint4*)(buf + 8);
}

// ---- K1 fused: MFMA scores + clamped-exp weighted pooling, single HBM read of feat.
// A tile (64 rows x 512 ch, bf16) persists in LDS for the whole kernel; pooling reads it back.
// Each block writes a private partial: part_g[bid][512] and part_s[bid] (no atomics).
__global__ __launch_bounds__(256)
void k_fused(const float* __restrict__ feat0, const float* __restrict__ feat1,
             const unsigned short* __restrict__ w1t,
             const float* __restrict__ b1_0, const float* __restrict__ w2_0, const float* __restrict__ b2_0,
             const float* __restrict__ b1_1, const float* __restrict__ w2_1, const float* __restrict__ b2_1,
             float* __restrict__ part_g, float* __restrict__ part_s, int npts)
{
    int bpt = npts / MB;
    int bid = blockIdx.x;
    int t  = bid / bpt;
    int mb = bid % bpt;
    const float* feat = t ? feat1 : feat0;
    const float* b1   = t ? b1_1 : b1_0;
    const float* w2   = t ? w2_1 : w2_0;
    float b2 = (t ? b2_1 : b2_0)[0];
    const unsigned short* wt = w1t + (size_t)t * NCOL * CDIM;

    __shared__ __align__(16) unsigned short As[MB * AROW];          // 66.56 KB, persistent
    __shared__ __align__(16) unsigned char Bs[NCOL * BSTR];         // 10.24 KB, rotating
    __shared__ float ew[MB];
    __shared__ float hsum[128][4];

    int tid = threadIdx.x;
    int wv = tid >> 6;
    int lane = tid & 63;
    int l15 = lane & 15, l4 = lane >> 4;

    f32x4 acc[8];
#pragma unroll
    for (int i = 0; i < 8; i++) acc[i] = (f32x4){0.f, 0.f, 0.f, 0.f};

    int row_base = mb * MB;
    int ar = tid >> 2;            // 0..63 A-staging row
    int ak = (tid & 3) * 8;       // k offset 0,8,16,24 within chunk
    int bc = tid >> 1;            // 0..127 B-staging col
    int bk = (tid & 1) * 16;      // k offset 0 or 16

#pragma unroll 1
    for (int step = 0; step < CDIM / BK; ++step) {
        int k0 = step * BK;
        // stage A chunk into persistent LDS tile (f32 -> bf16)
        {
            const float* src = feat + (size_t)(row_base + ar) * CDIM + k0 + ak;
            float4 v0 = *(const float4*)(src);
            float4 v1 = *(const float4*)(src + 4);
            float vv[8] = {v0.x, v0.y, v0.z, v0.w, v1.x, v1.y, v1.z, v1.w};
            union { short8v s; unsigned short u[8]; } tmp;
#pragma unroll
            for (int i = 0; i < 8; i++) {
                __hip_bfloat16 h = __float2bfloat16(vv[i]);
                tmp.u[i] = *(unsigned short*)&h;
            }
            *(short8v*)(&As[ar * AROW + k0 + ak]) = tmp.s;
        }
        // stage B chunk (bf16 copy, rotating buffer)
        {
            const unsigned short* src = wt + (size_t)bc * CDIM + k0 + bk;
            uint4 u0 = *(const uint4*)(src);
            uint4 u1 = *(const uint4*)(src + 8);
            *(uint4*)(Bs + bc * BSTR + bk * 2) = u0;
            *(uint4*)(Bs + bc * BSTR + bk * 2 + 16) = u1;
        }
        __syncthreads();
        bf16x8 afrag = *(const bf16x8*)(&As[(wv * 16 + l15) * AROW + k0 + l4 * 8]);
#pragma unroll
        for (int nt = 0; nt < 8; ++nt) {
            bf16x8 bfrag = *(const bf16x8*)(Bs + (nt * 16 + l15) * BSTR + l4 * 16);
            acc[nt] = __builtin_amdgcn_mfma_f32_16x16x32_bf16(afrag, bfrag, acc[nt], 0, 0, 0);
        }
        __syncthreads();
    }

    // epilogue: per-row score -> clamped exp weight
    float sp[4] = {0.f, 0.f, 0.f, 0.f};
#pragma unroll
    for (int nt = 0; nt < 8; ++nt) {
        int col = nt * 16 + l15;
        float bb = b1[col], ww = w2[col];
#pragma unroll
        for (int j = 0; j < 4; j++) {
            float h = acc[nt][j] + bb;
            h = fmaxf(h, 0.f);
            sp[j] += h * ww;
        }
    }
#pragma unroll
    for (int m = 1; m < 16; m <<= 1) {
#pragma unroll
        for (int j = 0; j < 4; j++) sp[j] += __shfl_xor(sp[j], m, 64);
    }
    if (l15 == 0) {
        int r = wv * 16 + l4 * 4;
#pragma unroll
        for (int j = 0; j < 4; j++) {
            float s = sp[j] + b2;
            s = fminf(fmaxf(s, -SCLAMP), SCLAMP);
            ew[r + j] = __expf(s);
        }
    }
    __syncthreads();

    // pooling from the persistent LDS tile: thread owns 4 channels, halves split rows
    {
        int half = tid >> 7;          // rows 0..31 / 32..63
        int tc = tid & 127;
        int c0 = tc * 4;
        f32x4 accv = (f32x4){0.f, 0.f, 0.f, 0.f};
        int r0 = half * 32;
#pragma unroll 8
        for (int r = 0; r < 32; ++r) {
            int row = r0 + r;
            float w = ew[row];
            ushort4 v = *(const ushort4*)(&As[row * AROW + c0]);
            union { unsigned int u; float f; } f0, f1, f2, f3;
            f0.u = (unsigned int)v.x << 16; f1.u = (unsigned int)v.y << 16;
            f2.u = (unsigned int)v.z << 16; f3.u = (unsigned int)v.w << 16;
            accv[0] += w * f0.f; accv[1] += w * f1.f;
            accv[2] += w * f2.f; accv[3] += w * f3.f;
        }
        if (half == 0) { hsum[tc][0] = accv[0]; hsum[tc][1] = accv[1];
                         hsum[tc][2] = accv[2]; hsum[tc][3] = accv[3]; }
        __syncthreads();
        if (half == 1) {
            float4 o;
            o.x = accv[0] + hsum[tc][0]; o.y = accv[1] + hsum[tc][1];
            o.z = accv[2] + hsum[tc][2]; o.w = accv[3] + hsum[tc][3];
            *(float4*)(part_g + (size_t)bid * CDIM + c0) = o;
        }
        if (tid < 64) {
            float e = ew[tid];
#pragma unroll
            for (int m = 1; m < 64; m <<= 1) e += __shfl_xor(e, m, 64);
            if (tid == 0) part_s[bid] = e;
        }
    }
}

// ---- K2: reduce 128 block-partials per (t,seg) -> gred[t*16+seg][512], sred[t*16+seg]
__global__ __launch_bounds__(256)
void k_reduce(const float* __restrict__ part_g, const float* __restrict__ part_s,
              float* __restrict__ gred, float* __restrict__ sred, int npts)
{
    int bid = blockIdx.x;            // 0..31: t = bid>>4, seg = bid&15
    int t = bid >> 4, seg = bid & 15;
    int bpt = npts / MB;             // 2048
    int base = t * bpt + seg * 128;  // 128 partials per segment
    int tid = threadIdx.x;
#pragma unroll
    for (int cpass = 0; cpass < 2; ++cpass) {
        int c = cpass * 256 + tid;
        float a = 0.f;
        for (int p = 0; p < 128; ++p)
            a += part_g[(size_t)(base + p) * CDIM + c];
        gred[(size_t)bid * CDIM + c] = a;
    }
    __shared__ float red[128];
    if (tid < 128) red[tid] = part_s[base + tid];
    __syncthreads();
    for (int h = 64; h; h >>= 1) { if (tid < h) red[tid] += red[tid + h]; __syncthreads(); }
    if (tid == 0) sred[bid] = red[0];
}

// ---------------- K3: head MLP, one block per batch row (k-split matvecs) ----------------
__global__ __launch_bounds__(256)
void k_head(const float* __restrict__ gred, const float* __restrict__ sred,
            const float* __restrict__ cat_emb, const int* __restrict__ cat_id,
            const float* __restrict__ rw1, const float* __restrict__ rb1,
            const float* __restrict__ g1, const float* __restrict__ be1,
            const float* __restrict__ rw2, const float* __restrict__ rb2,
            const float* __restrict__ g2, const float* __restrict__ be2,
            const float* __restrict__ rw3, const float* __restrict__ rb3,
            float* __restrict__ out)
{
    int b = blockIdx.x, tid = threadIdx.x;
    __shared__ float gf[1056];
    __shared__ float h1[256];
    __shared__ float h2[128];
    __shared__ float red[256];
    __shared__ float part[4][256];

    float inv0 = 1.0f / sred[0 * NSEG + b];
    float inv1 = 1.0f / sred[1 * NSEG + b];
    for (int i = tid; i < 512; i += 256) {
        gf[i]       = gred[(0 * NSEG + b) * CDIM + i] * inv0;
        gf[512 + i] = gred[(1 * NSEG + b) * CDIM + i] * inv1;
    }
    if (tid < 32) gf[1024 + tid] = cat_emb[cat_id[b] * 32 + tid];
    __syncthreads();

    // h1 = relu(LN(g @ rw1 + rb1)); matvec k-split across 4 waves
    int wv = tid >> 6, ln = tid & 63;
    {
        float a[4] = {0.f, 0.f, 0.f, 0.f};
        int kbeg = wv * 264, kend = kbeg + 264;
        for (int k = kbeg; k < kend; k++) {
            float gv = gf[k];
            const float* wr = rw1 + (size_t)k * 256;
#pragma unroll
            for (int j = 0; j < 4; j++) a[j] += gv * wr[ln + j * 64];
        }
#pragma unroll
        for (int j = 0; j < 4; j++) part[wv][ln + j * 64] = a[j];
    }
    __syncthreads();
    float a = rb1[tid] + part[0][tid] + part[1][tid] + part[2][tid] + part[3][tid];
    red[tid] = a; __syncthreads();
    for (int h = 128; h; h >>= 1) { if (tid < h) red[tid] += red[tid + h]; __syncthreads(); }
    float mu = red[0] / 256.f; __syncthreads();
    float d = a - mu;
    red[tid] = d * d; __syncthreads();
    for (int h = 128; h; h >>= 1) { if (tid < h) red[tid] += red[tid + h]; __syncthreads(); }
    float var = red[0] / 256.f; __syncthreads();
    float x = d * rsqrtf(var + 1e-5f) * g1[tid] + be1[tid];
    h1[tid] = fmaxf(x, 0.f);
    __syncthreads();

    // h2 = relu(LN(h1 @ rw2 + rb2)); k-split across 2 half-blocks
    {
        int half = tid >> 7, tc = tid & 127;
        float a2 = 0.f;
        int kbeg = half * 128, kend = kbeg + 128;
        for (int k = kbeg; k < kend; k++) a2 += h1[k] * rw2[(size_t)k * 128 + tc];
        part[half][tc] = a2;
    }
    __syncthreads();
    float a2 = 0.f;
    if (tid < 128) a2 = rb2[tid] + part[0][tid] + part[1][tid];
    red[tid] = (tid < 128) ? a2 : 0.f; __syncthreads();
    for (int h = 128; h; h >>= 1) { if (tid < h) red[tid] += red[tid + h]; __syncthreads(); }
    float mu2 = red[0] / 128.f; __syncthreads();
    float d2 = a2 - mu2;
    red[tid] = (tid < 128) ? d2 * d2 : 0.f; __syncthreads();
    for (int h = 128; h; h >>= 1) { if (tid < h) red[tid] += red[tid + h]; __syncthreads(); }
    float var2 = red[0] / 128.f; __syncthreads();
    if (tid < 128) {
        float x2 = d2 * rsqrtf(var2 + 1e-5f) * g2[tid] + be2[tid];
        h2[tid] = fmaxf(x2, 0.f);
    }
    __syncthreads();
    if (tid < 3) {
        float o = rb3[tid];
        for (int k = 0; k < 128; k++) o += h2[k] * rw3[k * 3 + tid];
        out[b * 3 + tid] = o;
    }
}

extern "C" void kernel_launch(void* const* d_in, const int* in_sizes, int n_in,
                              void* d_out, int out_size, void* d_ws, size_t ws_size,
                              hipStream_t stream)
{
    const float* local_feat  = (const float*)d_in[0];
    const float* parent_feat = (const float*)d_in[1];
    const int*   cat_id = (const int*)d_in[4];
    const float* att_w1 = (const float*)d_in[5];
    const float* att_b1 = (const float*)d_in[6];
    const float* att_w2 = (const float*)d_in[7];
    const float* att_b2 = (const float*)d_in[8];
    const float* patt_w1 = (const float*)d_in[9];
    const float* patt_b1 = (const float*)d_in[10];
    const float* patt_w2 = (const float*)d_in[11];
    const float* patt_b2 = (const float*)d_in[12];
    const float* cat_emb = (const float*)d_in[13];
    const float* rw1 = (const float*)d_in[14]; const float* rb1 = (const float*)d_in[15];
    const float* ln1_g = (const float*)d_in[16]; const float* ln1_b = (const float*)d_in[17];
    const float* rw2 = (const float*)d_in[18]; const float* rb2 = (const float*)d_in[19];
    const float* ln2_g = (const float*)d_in[20]; const float* ln2_b = (const float*)d_in[21];
    const float* rw3 = (const float*)d_in[22]; const float* rb3 = (const float*)d_in[23];

    int npts = in_sizes[0] / CDIM;   // 131072
    int nblk = 2 * (npts / MB);      // 4096

    char* ws = (char*)d_ws;
    unsigned short* w1t = (unsigned short*)ws;                         // 256 KB
    float* part_g = (float*)(ws + 262144);                             // 4096*512*4 = 8 MB
    float* part_s = (float*)(ws + 262144 + (size_t)nblk * CDIM * 4);   // 4096*4 = 16 KB
    float* gred   = (float*)((char*)part_s + (size_t)nblk * 4);        // 32*512*4 = 64 KB
    float* sred   = (float*)((char*)gred + 32 * CDIM * 4);             // 128 B

    k_prep<<<32, 256, 0, stream>>>(att_w1, patt_w1, w1t);
    k_fused<<<nblk, 256, 0, stream>>>(local_feat, parent_feat, w1t,
                                      att_b1, att_w2, att_b2,
                                      patt_b1, patt_w2, patt_b2, part_g, part_s, npts);
    k_reduce<<<32, 256, 0, stream>>>(part_g, part_s, gred, sred, npts);
    k_head<<<16, 256, 0, stream>>>(gred, sred, cat_emb, cat_id, rw1, rb1, ln1_g, ln1_b,
                                   rw2, rb2, ln2_g, ln2_b, rw3, rb3, (float*)d_out);
}